// Round 1
// baseline (4324.728 us; speedup 1.0000x reference)
//
#include <hip/hip_runtime.h>

#define N_ROWS 65536
#define K_CB   4096
#define D_MODEL 512

#define BM  64      // rows per block
#define BKT 128     // codewords per K-tile
#define BD  32      // D-chunk staged in LDS
#define SD  36      // padded LDS stride (floats): 144B, 16B-aligned, 2-way-bank max

// ---------------- wsq precompute: one wave per codeword ----------------
__global__ __launch_bounds__(256) void wsq_kernel(const float* __restrict__ w,
                                                  float* __restrict__ wsq) {
    int k    = blockIdx.x * 4 + (threadIdx.x >> 6);
    int lane = threadIdx.x & 63;
    const float4* row = (const float4*)(w + (size_t)k * D_MODEL);
    float s = 0.f;
    // 512 floats = 128 float4; each lane handles 2
    #pragma unroll
    for (int c = 0; c < 2; ++c) {
        float4 v = row[lane + 64 * c];
        s += v.x * v.x + v.y * v.y + v.z * v.z + v.w * v.w;
    }
    #pragma unroll
    for (int m = 32; m; m >>= 1) s += __shfl_xor(s, m, 64);
    if (lane == 0) wsq[k] = s;
}

// ---------------- fused GEMM + argmin + gather ----------------
__global__ __launch_bounds__(256) void vq_kernel(const float* __restrict__ z,
                                                 const float* __restrict__ w,
                                                 const float* __restrict__ wsq,
                                                 float* __restrict__ out_idx,
                                                 float* __restrict__ out_q) {
    __shared__ float zs[BM][SD];
    __shared__ float ws[BKT][SD];
    __shared__ int   idx_s[BM];

    const int tid = threadIdx.x;
    const int tx  = tid & 15;   // 16 lanes -> 128 cols (k = k0 + 16*j + tx)
    const int ty  = tid >> 4;   // 16 groups -> 64 rows (m = m0 + 4*ty + i)
    const int m0  = blockIdx.x * BM;

    float minv[4];
    int   mini[4];
    #pragma unroll
    for (int i = 0; i < 4; ++i) { minv[i] = 3.4e38f; mini[i] = 0; }

    for (int k0 = 0; k0 < K_CB; k0 += BKT) {
        float acc[4][8];
        #pragma unroll
        for (int i = 0; i < 4; ++i)
            #pragma unroll
            for (int j = 0; j < 8; ++j) acc[i][j] = 0.f;

        for (int d0 = 0; d0 < D_MODEL; d0 += BD) {
            __syncthreads();   // previous tile's compute done before overwrite
            // ---- stage z tile: 64 rows x 32 cols = 512 float4, 2 per thread
            {
                int r = tid >> 3;          // 0..31
                int c = tid & 7;           // float4 column
                #pragma unroll
                for (int it = 0; it < 2; ++it, r += 32) {
                    float4 v = ((const float4*)(z + (size_t)(m0 + r) * D_MODEL + d0))[c];
                    *(float4*)&zs[r][c * 4] = v;
                }
            }
            // ---- stage w tile: 128 rows x 32 cols = 1024 float4, 4 per thread
            {
                int r = tid >> 3;
                int c = tid & 7;
                #pragma unroll
                for (int it = 0; it < 4; ++it, r += 32) {
                    float4 v = ((const float4*)(w + (size_t)(k0 + r) * D_MODEL + d0))[c];
                    *(float4*)&ws[r][c * 4] = v;
                }
            }
            __syncthreads();
            // ---- accumulate 4x8 outer product over this D-chunk
            #pragma unroll
            for (int d = 0; d < BD; d += 4) {
                float4 zv[4];
                #pragma unroll
                for (int i = 0; i < 4; ++i) zv[i] = *(const float4*)&zs[ty * 4 + i][d];
                float4 wv[8];
                #pragma unroll
                for (int j = 0; j < 8; ++j) wv[j] = *(const float4*)&ws[j * 16 + tx][d];
                #pragma unroll
                for (int i = 0; i < 4; ++i)
                    #pragma unroll
                    for (int j = 0; j < 8; ++j) {
                        acc[i][j] = fmaf(zv[i].x, wv[j].x, acc[i][j]);
                        acc[i][j] = fmaf(zv[i].y, wv[j].y, acc[i][j]);
                        acc[i][j] = fmaf(zv[i].z, wv[j].z, acc[i][j]);
                        acc[i][j] = fmaf(zv[i].w, wv[j].w, acc[i][j]);
                    }
            }
        }
        // ---- argmin update: s = wsq[k] - 2*dot  (zsq is row-constant, dropped)
        #pragma unroll
        for (int j = 0; j < 8; ++j) {        // j ascending => k ascending (first-min kept)
            int   k  = k0 + j * 16 + tx;
            float wq = wsq[k];
            #pragma unroll
            for (int i = 0; i < 4; ++i) {
                float s = fmaf(-2.f, acc[i][j], wq);
                if (s < minv[i]) { minv[i] = s; mini[i] = k; }
            }
        }
    }

    // ---- reduce argmin across the 16 tx lanes (np.argmin tie-break: lowest index)
    #pragma unroll
    for (int i = 0; i < 4; ++i) {
        float v  = minv[i];
        int   ix = mini[i];
        #pragma unroll
        for (int m = 8; m; m >>= 1) {
            float ov = __shfl_xor(v, m, 16);
            int   oi = __shfl_xor(ix, m, 16);
            if (ov < v || (ov == v && oi < ix)) { v = ov; ix = oi; }
        }
        if (tx == 0) {
            int row = ty * 4 + i;
            out_idx[m0 + row] = (float)ix;
            idx_s[row] = ix;
        }
    }
    __syncthreads();

    // ---- gather: out_q[row] = weight[idx_s[row]]  (rows are 2KB, L2-hot)
    const float4* w4 = (const float4*)w;
    float4*       o4 = (float4*)out_q;
    for (int t = tid; t < BM * 128; t += 256) {
        int r = t >> 7;
        int c = t & 127;
        o4[(size_t)(m0 + r) * 128 + c] = w4[(size_t)idx_s[r] * 128 + c];
    }
}

extern "C" void kernel_launch(void* const* d_in, const int* in_sizes, int n_in,
                              void* d_out, int out_size, void* d_ws, size_t ws_size,
                              hipStream_t stream) {
    const float* z = (const float*)d_in[0];
    const float* w = (const float*)d_in[1];
    float* out     = (float*)d_out;
    float* out_idx = out;            // N floats (indices as float values)
    float* out_q   = out + N_ROWS;   // N*D floats
    float* wsq     = (float*)d_ws;   // 4096 floats = 16 KB scratch

    wsq_kernel<<<K_CB / 4, 256, 0, stream>>>(w, wsq);
    vq_kernel<<<N_ROWS / BM, 256, 0, stream>>>(z, w, wsq, out_idx, out_q);
}